// Round 8
// baseline (498.796 us; speedup 1.0000x reference)
//
#include <hip/hip_runtime.h>
#include <stdint.h>

#define Bb 8
#define Cc 256
#define Nn 2304
#define KSPLIT 3
#define TPS 24   // 32-key tiles per split: 2304/32/3
#define L2E 1.44269504088896f

typedef unsigned short u16;
typedef _Float16 h16;
typedef h16  h16x8 __attribute__((ext_vector_type(8)));
typedef u16  u16x8 __attribute__((ext_vector_type(8)));
typedef float f32x4 __attribute__((ext_vector_type(4)));

static __device__ __forceinline__ u16 f2h(float f) {
  return __builtin_bit_cast(u16, (h16)f);
}
static __device__ __forceinline__ h16x8 ash(u16x8 v) {
  return __builtin_bit_cast(h16x8, v);
}
static __device__ __forceinline__ f32x4 mfma16(u16x8 a, u16x8 b, f32x4 c) {
  return __builtin_amdgcn_mfma_f32_16x16x32_f16(ash(a), ash(b), c, 0, 0, 0);
}

// DPP row_ror reductions over 16 lanes (VALU pipe)
template <int CTRL>
static __device__ __forceinline__ float dppmov(float x) {
  return __builtin_bit_cast(float,
      __builtin_amdgcn_mov_dpp(__builtin_bit_cast(int, x), CTRL, 0xF, 0xF, true));
}
static __device__ __forceinline__ float rowmax16(float x) {
  x = fmaxf(x, dppmov<0x121>(x));
  x = fmaxf(x, dppmov<0x122>(x));
  x = fmaxf(x, dppmov<0x124>(x));
  x = fmaxf(x, dppmov<0x128>(x));
  return x;
}
static __device__ __forceinline__ float rowsum16(float x) {
  x += dppmov<0x121>(x);
  x += dppmov<0x122>(x);
  x += dppmov<0x124>(x);
  x += dppmov<0x128>(x);
  return x;
}

// ---------------------------------------------------------------------------
// Projection v8 (prep folded in: W converted fp32->fp16 during LDS staging).
// Input tile f32x4-loaded, transposed through LDS (pad-264). Epilogues
// transpose through LDS for coalesced u16x8 stores.
// z=0: Q [B][N][C], z=1: K [B][N][C], z=2: V^T [B][C][N]. grid (8,36,3).
// ---------------------------------------------------------------------------
#define SA_SZ 18432   // union: input 64x264 u16 (16896) / z2-epi 256x72 (18432)
__global__ __launch_bounds__(256, 2) void proj_kernel(
    const float* __restrict__ x, const float* __restrict__ y,
    const float* __restrict__ Wq, const float* __restrict__ Wk,
    const float* __restrict__ Wv,
    const float* __restrict__ bq, const float* __restrict__ bk,
    const float* __restrict__ bv,
    u16* __restrict__ Qf, u16* __restrict__ Kf, u16* __restrict__ Vf)
{
  __shared__ u16 sA[SA_SZ];
  __shared__ u16 sW[32 * 256];
  const int t    = threadIdx.x;
  const int b    = blockIdx.x;
  const int q0   = blockIdx.y * 64;
  const int z    = blockIdx.z;
  const int lane = t & 63;
  const int w    = t >> 6;
  const int quad = lane >> 4;
  const int l15  = lane & 15;
  const float* WZ = (z == 0) ? Wq : (z == 1) ? Wk : Wv;

  // ---- stage input tile: f32x4 token-quad loads -> [tok][c] u16, pad 264 ----
  {
    const float* src = (z == 0) ? x : y;
    const float* pc = src + ((size_t)b * Cc + t) * Nn + q0;
#pragma unroll 4
    for (int it = 0; it < 16; ++it) {
      const f32x4 v4 = *(const f32x4*)(pc + it * 4);
#pragma unroll
      for (int j = 0; j < 4; ++j)
        sA[(it * 4 + j) * 264 + t] = f2h(v4[j]);
    }
  }
  __syncthreads();

  // ---- token fragments from LDS (A-operand for z<2, B-operand for z==2) ----
  u16x8 af[8];
  {
    const int trow = w * 16 + l15;
#pragma unroll
    for (int kc = 0; kc < 8; ++kc)
      af[kc] = *(const u16x8*)(sA + trow * 264 + kc * 32 + quad * 8);
  }

  f32x4 acc[16];
#pragma unroll
  for (int i = 0; i < 16; ++i) acc[i] = (f32x4){0.f, 0.f, 0.f, 0.f};

  // ---- 8 rounds of 32 c_out rows; W fp32 loaded, converted, swizzled ----
#pragma unroll 1
  for (int rg = 0; rg < 8; ++rg) {
    __syncthreads();
#pragma unroll
    for (int it = 0; it < 4; ++it) {
      const int id = it * 256 + t;
      const int row = id >> 5, gch = id & 31;
      const float* wp = WZ + (size_t)(rg * 32 + row) * 256 + gch * 8;
      const f32x4 a = *(const f32x4*)wp;
      const f32x4 c = *(const f32x4*)(wp + 4);
      u16x8 v;
#pragma unroll
      for (int j = 0; j < 4; ++j) { v[j] = f2h(a[j]); v[j + 4] = f2h(c[j]); }
      *(u16x8*)(sW + row * 256 + ((gch ^ (row & 7)) << 3)) = v;
    }
    __syncthreads();
    if (z < 2) {
#pragma unroll
      for (int cbl = 0; cbl < 2; ++cbl) {
        const int rl = cbl * 16 + l15;
        f32x4 a = acc[rg * 2 + cbl];
#pragma unroll
        for (int kc = 0; kc < 8; ++kc) {
          const u16x8 bf = *(const u16x8*)(sW + rl * 256 + (((kc * 4 + quad) ^ (rl & 7)) << 3));
          a = mfma16(af[kc], bf, a);
        }
        acc[rg * 2 + cbl] = a;
      }
    } else {
#pragma unroll
      for (int mt = 0; mt < 2; ++mt) {
        const int rl = mt * 16 + l15;
        f32x4 a = acc[rg * 2 + mt];
#pragma unroll
        for (int kc = 0; kc < 8; ++kc) {
          const u16x8 wfr = *(const u16x8*)(sW + rl * 256 + (((kc * 4 + quad) ^ (rl & 7)) << 3));
          a = mfma16(wfr, af[kc], a);
        }
        acc[rg * 2 + mt] = a;
      }
    }
  }

  // ---- epilogue: transpose through sA, coalesced u16x8 stores ----
  if (z < 2) {
    const float* bias = (z == 0) ? bq : bk;
    u16* O = (z == 0) ? Qf : Kf;
#pragma unroll
    for (int i = 0; i < 16; ++i) {
      const int co = i * 16 + l15;
      const float bs = bias[co];
      const int chunk = co >> 3;
      const int wi = co & 7;
#pragma unroll
      for (int r = 0; r < 4; ++r) {
        const int tok = w * 16 + quad * 4 + r;
        sA[tok * 264 + ((chunk ^ (tok & 3)) << 3) + wi] = f2h(acc[i][r] + bs);
      }
    }
    __syncthreads();
#pragma unroll
    for (int it = 0; it < 8; ++it) {
      const int tok = w * 16 + (lane >> 2);
      const int ch = (lane & 3) + 4 * it;
      const u16x8 v = *(const u16x8*)(sA + tok * 264 + ((ch ^ (tok & 3)) << 3));
      *(u16x8*)(O + ((size_t)b * Nn + q0 + tok) * 256 + ch * 8) = v;
    }
  } else {
#pragma unroll
    for (int i = 0; i < 16; ++i) {
#pragma unroll
      for (int r = 0; r < 4; ++r) {
        const int co = i * 16 + quad * 4 + r;
        sA[co * 72 + w * 16 + l15] = f2h(acc[i][r] + bv[co]);
      }
    }
    __syncthreads();
#pragma unroll
    for (int it = 0; it < 8; ++it) {
      const int id = it * 256 + t;
      const int co = id >> 3, tc = id & 7;
      const u16x8 v = *(const u16x8*)(sA + co * 72 + tc * 8);
      *(u16x8*)(Vf + ((size_t)b * Cc + co) * Nn + q0 + tc * 8) = v;
    }
  }
}

// ---------------------------------------------------------------------------
// Flash attention v8 = R6 structure (the 177-us winner) with KSPLIT=3 and
// __launch_bounds__(256,4): grid (8,36,3)=864 blocks -> 108/XCD, all
// resident (LDS 36 KB -> 4 blocks/CU) -> no L2 thrash (R7 lesson), ~3.4
// blocks/CU vs R6's 2.25. 32-key tiles, register-prefetch pipeline.
// LDS 36 KB: sK [32][256], sV [256 c][32 keys], sP 4x512.
// ---------------------------------------------------------------------------
__global__ __launch_bounds__(256, 4) void attn_kernel(
    const u16* __restrict__ Qf, const u16* __restrict__ Kf,
    const u16* __restrict__ Vf, float* __restrict__ Opart,
    float* __restrict__ Ml)
{
  __shared__ u16 sK[32 * 256];   // 16 KB
  __shared__ u16 sV[256 * 32];   // 16 KB
  __shared__ u16 sP[4 * 512];    //  4 KB
  const int t    = threadIdx.x;
  const int b    = blockIdx.x;
  const int q0   = blockIdx.y * 64;
  const int sp   = blockIdx.z;
  const int lane = t & 63;
  const int w    = t >> 6;
  const int quad = lane >> 4;
  const int l15  = lane & 15;

  // Q A-frags
  u16x8 qf[8];
  {
    const size_t qrow = ((size_t)b * Nn + q0 + w * 16 + l15) * Cc;
#pragma unroll
    for (int kc = 0; kc < 8; ++kc)
      qf[kc] = *(const u16x8*)(Qf + qrow + kc * 32 + quad * 8);
  }

  f32x4 o[16];
#pragma unroll
  for (int i = 0; i < 16; ++i) o[i] = (f32x4){0.f, 0.f, 0.f, 0.f};
  float mrow[4] = {-3e38f, -3e38f, -3e38f, -3e38f};
  float lrow[4] = {0.f, 0.f, 0.f, 0.f};

  const u16* Kb = Kf + (size_t)b * Nn * Cc;
  const u16* Vb = Vf + (size_t)b * Cc * Nn;
  const int gl = (l15 & 3) ^ ((l15 >> 2) & 3);

  // staging geometry (per-thread constants)
  const int krow = t >> 5;               // K: row 0..7 (+8*it)
  const int kch  = t & 31;               // K: global chunk (coalesced)
  const int vc   = t >> 2;               // V: c row 0..63 (+64*it)
  const int vp   = t & 3;                // V: chunk

  u16x8 pk[4], pv[4];
  {
    const size_t kg0 = (size_t)sp * TPS * 32;
#pragma unroll
    for (int it = 0; it < 4; ++it) {
      pk[it] = *(const u16x8*)(Kb + (kg0 + krow + it * 8) * Cc + kch * 8);
      pv[it] = *(const u16x8*)(Vb + (size_t)(it * 64 + vc) * Nn + kg0 + vp * 8);
    }
  }

#pragma unroll 1
  for (int kb = 0; kb < TPS; ++kb) {
    __syncthreads();   // prev tile's LDS reads done
    // ---- regs -> LDS (swizzled on the LDS side) ----
#pragma unroll
    for (int it = 0; it < 4; ++it) {
      const int row = krow + it * 8;
      *(u16x8*)(sK + row * 256 + ((kch ^ (row & 7)) << 3)) = pk[it];
      const int c = it * 64 + vc;
      *(u16x8*)(sV + c * 32 + ((vp ^ ((c >> 1) & 3)) << 3)) = pv[it];
    }
    __syncthreads();
    // ---- prefetch next tile (drains at next tile's ds_write) ----
    if (kb + 1 < TPS) {
      const size_t kg0 = ((size_t)sp * TPS + kb + 1) * 32;
#pragma unroll
      for (int it = 0; it < 4; ++it) {
        pk[it] = *(const u16x8*)(Kb + (kg0 + krow + it * 8) * Cc + kch * 8);
        pv[it] = *(const u16x8*)(Vb + (size_t)(it * 64 + vc) * Nn + kg0 + vp * 8);
      }
    }

    // ---- S = Q K^T (two 16-key blocks) ----
    f32x4 s0 = {0.f, 0.f, 0.f, 0.f}, s1 = s0;
#pragma unroll
    for (int kc = 0; kc < 8; ++kc) {
      const int ch = ((kc * 4 + quad) ^ (l15 & 7)) << 3;
      const u16x8 k0 = *(const u16x8*)(sK + l15 * 256 + ch);
      const u16x8 k1 = *(const u16x8*)(sK + (16 + l15) * 256 + ch);
      s0 = mfma16(qf[kc], k0, s0);
      s1 = mfma16(qf[kc], k1, s1);
    }

    // ---- online softmax (4 independent DPP chains) ----
    float m0[4], al[4], sums[4];
#pragma unroll
    for (int r = 0; r < 4; ++r) m0[r] = fmaxf(s0[r], s1[r]);
#pragma unroll
    for (int r = 0; r < 4; ++r) m0[r] = rowmax16(m0[r]);
#pragma unroll
    for (int r = 0; r < 4; ++r) {
      const float mn = fmaxf(mrow[r], m0[r]);
      al[r] = exp2f((mrow[r] - mn) * L2E);
      mrow[r] = mn;
      const float p0 = exp2f((s0[r] - mn) * L2E);
      const float p1 = exp2f((s1[r] - mn) * L2E);
      s0[r] = p0; s1[r] = p1;
      sums[r] = p0 + p1;
    }
#pragma unroll
    for (int r = 0; r < 4; ++r) sums[r] = rowsum16(sums[r]);
#pragma unroll
    for (int r = 0; r < 4; ++r) lrow[r] = lrow[r] * al[r] + sums[r];

    if (__any((al[0] < 1.f) | (al[1] < 1.f) | (al[2] < 1.f) | (al[3] < 1.f))) {
#pragma unroll
      for (int i = 0; i < 16; ++i) {
#pragma unroll
        for (int r = 0; r < 4; ++r) o[i][r] *= al[r];
      }
    }

    // ---- P: C/D -> sP (wave-local) -> A layout ----
    {
      u16* P = sP + w * 512;
      const int kch0 = l15 >> 3;
#pragma unroll
      for (int r = 0; r < 4; ++r) {
        const int row = quad * 4 + r;
        const int gx = r ^ quad;
        P[row * 32 + ((kch0 ^ gx) << 3) + (l15 & 7)] = f2h(s0[r]);
        P[row * 32 + (((2 + kch0) ^ gx) << 3) + (l15 & 7)] = f2h(s1[r]);
      }
    }
    __builtin_amdgcn_s_waitcnt(0xC07F);  // lgkmcnt(0)
    const u16x8 pf = *(const u16x8*)(sP + w * 512 + l15 * 32 + ((quad ^ gl) << 3));

    // ---- O += P V (16 independent accumulators) ----
#pragma unroll
    for (int cb2 = 0; cb2 < 16; ++cb2) {
      const int c = cb2 * 16 + l15;
      const u16x8 vf = *(const u16x8*)(sV + c * 32 + ((quad ^ ((c >> 1) & 3)) << 3));
      o[cb2] = mfma16(pf, vf, o[cb2]);
    }
  }

  // ---- epilogue: unnormalized partials ----
  float* Ob = Opart + ((size_t)sp * Bb + b) * (size_t)Cc * Nn;
#pragma unroll
  for (int cb2 = 0; cb2 < 16; ++cb2) {
    const int c = cb2 * 16 + l15;
    *(f32x4*)(Ob + (size_t)c * Nn + q0 + w * 16 + quad * 4) = o[cb2];
  }
  if (l15 == 0) {
    float* mlb = Ml + ((size_t)sp * Bb + b) * (size_t)Nn * 2;
#pragma unroll
    for (int r = 0; r < 4; ++r) {
      const int n = q0 + w * 16 + quad * 4 + r;
      mlb[n * 2]     = mrow[r];
      mlb[n * 2 + 1] = lrow[r];
    }
  }
}

// ---------------------------------------------------------------------------
// Merge the 3 K-split partials.
// ---------------------------------------------------------------------------
__global__ void merge_kernel(const float* __restrict__ Opart,
                             const float* __restrict__ Ml,
                             float* __restrict__ out)
{
  const int idx = blockIdx.x * 256 + threadIdx.x;  // Bb*Cc*576
  const int n4 = idx % 576;
  const int bc = idx / 576;
  const int b  = bc >> 8;
  const size_t NCt = (size_t)Bb * Cc * Nn;
  const size_t ooff = (size_t)bc * Nn + n4 * 4;
  f32x4 os[KSPLIT];
  float mm[KSPLIT][4], ll[KSPLIT][4];
#pragma unroll
  for (int s = 0; s < KSPLIT; ++s) {
    os[s] = *(const f32x4*)(Opart + ooff + (size_t)s * NCt);
    const float* mlb = Ml + ((size_t)s * Bb + b) * (size_t)Nn * 2;
#pragma unroll
    for (int j = 0; j < 4; ++j) {
      mm[s][j] = mlb[(n4 * 4 + j) * 2];
      ll[s][j] = mlb[(n4 * 4 + j) * 2 + 1];
    }
  }
  f32x4 r;
#pragma unroll
  for (int j = 0; j < 4; ++j) {
    float m = mm[0][j];
#pragma unroll
    for (int s = 1; s < KSPLIT; ++s) m = fmaxf(m, mm[s][j]);
    float num = 0.f, den = 0.f;
#pragma unroll
    for (int s = 0; s < KSPLIT; ++s) {
      const float wgt = exp2f((mm[s][j] - m) * L2E);
      num += os[s][j] * wgt;
      den += ll[s][j] * wgt;
    }
    r[j] = num / den;
  }
  *(f32x4*)(out + ooff) = r;
}

extern "C" void kernel_launch(void* const* d_in, const int* in_sizes, int n_in,
                              void* d_out, int out_size, void* d_ws, size_t ws_size,
                              hipStream_t stream) {
  const float* x  = (const float*)d_in[0];
  const float* y  = (const float*)d_in[1];
  const float* Wq = (const float*)d_in[2];
  const float* bq = (const float*)d_in[3];
  const float* Wk = (const float*)d_in[4];
  const float* bk = (const float*)d_in[5];
  const float* Wv = (const float*)d_in[6];
  const float* bv = (const float*)d_in[7];
  float* out = (float*)d_out;

  const size_t NC = (size_t)Bb * Nn * Cc;   // 4,718,592
  u16* Qf = (u16*)d_ws;
  u16* Kf = Qf + NC;
  u16* Vf = Kf + NC;
  float* Opart = (float*)(Vf + NC);              // KSPLIT*NC f32
  float* Ml    = Opart + (size_t)KSPLIT * NC;    // KSPLIT*Bb*Nn*2 f32

  hipLaunchKernelGGL(proj_kernel, dim3(Bb, 36, 3), dim3(256), 0, stream,
                     x, y, Wq, Wk, Wv, bq, bk, bv, Qf, Kf, Vf);
  hipLaunchKernelGGL(attn_kernel, dim3(Bb, 36, KSPLIT), dim3(256), 0, stream,
                     Qf, Kf, Vf, Opart, Ml);
  hipLaunchKernelGGL(merge_kernel, dim3(4608), dim3(256), 0, stream,
                     Opart, Ml, out);
}